// Round 20
// baseline (141.725 us; speedup 1.0000x reference)
//
#include <hip/hip_runtime.h>
#include <stdint.h>

#define N_NODES   50000
#define N_EDGES   400000
#define IN_FEATS  16
#define HIDDEN    32
#define K1        128      // EDGE_MLP_HID
#define NOUT      512      // IN_FEATS*HIDDEN
#define N_CLS     100000
#define CAP       40       // max degree slots (Poisson(8): P(deg>40) ~ 0)
#define TILE_E    256
#define FUSED_BLOCKS ((N_EDGES + TILE_E - 1) / TILE_E)   // 1563 (last block half-full)

typedef float  f32x4  __attribute__((ext_vector_type(4)));
typedef __bf16 bf16x8 __attribute__((ext_vector_type(8)));

__device__ __forceinline__ unsigned short f32_bf16(float f) {
    union { float f; uint32_t u; } c; c.f = f;
    uint32_t r = c.u + 0x7fffu + ((c.u >> 16) & 1u);
    return (unsigned short)(r >> 16);
}

// async global->LDS, 16B per lane; LDS dest is wave-uniform base + lane*16
__device__ __forceinline__ void gload_lds16(const unsigned short* g, unsigned short* l) {
    __builtin_amdgcn_global_load_lds(
        (const __attribute__((address_space(1))) unsigned int*)(g),
        (__attribute__((address_space(3))) unsigned int*)(l),
        16, 0, 0);
}

__device__ __forceinline__ bf16x8 pack_bf16x8(float4 f0, float4 f1) {
    unsigned short t8[8] = { f32_bf16(f0.x), f32_bf16(f0.y), f32_bf16(f0.z), f32_bf16(f0.w),
                             f32_bf16(f1.x), f32_bf16(f1.y), f32_bf16(f1.z), f32_bf16(f1.w) };
    return *reinterpret_cast<const bf16x8*>(t8);
}

// ---- merged prep: weights transpose/convert + dst bucketing (R18-coalesced reads) ----
// w2ts: W2 [128,512] -> bf16 [512,128], PRE-SWIZZLED k ^= (n&15)<<3 (R10/R11-verified).
// w1t:  W1 [16,128] -> bf16 [128,32] (K padded 16->32), linear.
// w1c:  cls_w1 [80,32] -> bf16 [32 hid][96 K] (K padded 80->96), for MFMA classifier.
__global__ void prep_and_slots(const float* __restrict__ w2, const float* __restrict__ w1,
                               const float* __restrict__ cw1, const int* __restrict__ dst,
                               unsigned short* __restrict__ w2ts, unsigned short* __restrict__ w1t,
                               unsigned short* __restrict__ w1c,
                               int* __restrict__ cursor, int* __restrict__ slots) {
    int gid = blockIdx.x * 256 + threadIdx.x;
    if (gid < NOUT * K1) {
        int k = gid >> 9, n = gid & 511;               // read w2[k*512+n] coalesced in n
        w2ts[n * 128 + (k ^ ((n & 15) << 3))] = f32_bf16(w2[k * 512 + n]);
    } else if (gid < NOUT * K1 + 4096) {
        int t = gid - NOUT * K1;
        int k = t >> 7, n = t & 127;                   // read w1[k*128+n] coalesced in n
        w1t[n * 32 + k] = (k < 16) ? f32_bf16(w1[k * 128 + n]) : (unsigned short)0;
    } else if (gid < NOUT * K1 + 4096 + 3072) {
        int t = gid - (NOUT * K1 + 4096);
        int k = t >> 5, hid = t & 31;                  // read cw1[k*32+hid] coalesced in hid
        w1c[hid * 96 + k] = (k < 80) ? f32_bf16(cw1[k * 32 + hid]) : (unsigned short)0;
    }
    if (gid < N_EDGES) {
        int d = dst[gid];
        int pos = atomicAdd(&cursor[d], 1);
        if (pos < CAP) slots[d * CAP + pos] = gid;
    }
}

// ---- fused: edge MLP (MFMA, swapped operands) + per-edge matvec ----
// Champion barrier skeleton, et-extent 2 -> 4: TILE_E=256, 4 waves x 64 edges each.
// Each bw ds_read feeds 4 MFMA chains (per-edge LDS reads halve vs R19). relu1 region
// is 64KB; B double-buffers overlay it after aF extraction. 64KB LDS -> 2 blocks/CU
// x 8 waves = 16 waves/CU (~50% occ). (256,2) caps VGPR at 256; natural ~170, no
// spill possible (R13 rule: never force VGPR below natural demand).
// Tail: last block covers 128 edges; loads clamped, stores guarded.
__global__ __launch_bounds__(256, 2) void fused_msg(
    const float* __restrict__ nf, const float* __restrict__ ef,
    const int* __restrict__ src,
    const unsigned short* __restrict__ w1t, const float* __restrict__ b1,
    const unsigned short* __restrict__ w2ts, const float* __restrict__ b2,
    float* __restrict__ msg)
{
    __shared__ __align__(16) unsigned short sAmem[256 * 128]; // 64KB: relu1, then B buf0|buf1

    const int tid  = threadIdx.x;
    const int lane = tid & 63;
    const int w    = tid >> 6;      // wave 0..3
    const int l15  = lane & 15;
    const int lg   = lane >> 4;     // 0..3
    const int key  = (l15 & 7) << 3;   // relu1 (sA) swizzle key (write+read paired)
    const int key2 = l15 << 3;         // B swizzle key, full 4-bit (matches w2ts pre-swizzle)
    const int e0   = blockIdx.x * TILE_E;

    unsigned short* buf0 = sAmem;            // 16KB (64 rows x 128)
    unsigned short* buf1 = sAmem + 8192;     // 16KB

    // stage 64-col chunk cc (8192 elems) linearly: 4 waves x 4 calls x 1KB
    auto stage = [&](int cc, unsigned short* buf) {
        #pragma unroll
        for (int i = 0; i < 4; ++i)
            gload_lds16(&w2ts[cc * 8192 + (w * 4 + i) * 512 + lane * 8],
                        &buf[(w * 4 + i) * 512]);
    };

    // this wave's 64 edges: et = 0..3, edge = e0 + w*64 + et*16 + l15 (clamped for tail)
    int sa[4];
    bool ve[4];
    int eidx4[4];
    #pragma unroll
    for (int et = 0; et < 4; ++et) {
        int e = e0 + w * 64 + et * 16 + l15;
        ve[et] = e < N_EDGES;
        eidx4[et] = ve[et] ? e : (N_EDGES - 1);
        sa[et] = src[eidx4[et]];
    }

    // ---------- P1 (own-edges): relu1 for this wave's 64 edges across ALL 8 n1-tiles ----------
    {
        bf16x8 aef[4];
        #pragma unroll
        for (int et = 0; et < 4; ++et) {
            if (lg < 2) {
                float4 f0 = *reinterpret_cast<const float4*>(&ef[eidx4[et] * 16 + lg * 8]);
                float4 f1 = *reinterpret_cast<const float4*>(&ef[eidx4[et] * 16 + lg * 8 + 4]);
                aef[et] = pack_bf16x8(f0, f1);
            } else {
                aef[et] = bf16x8(0);   // K-pad (k >= 16)
            }
        }
        #pragma unroll
        for (int t = 0; t < 8; ++t) {
            bf16x8 w1f = *reinterpret_cast<const bf16x8*>(&w1t[(t * 16 + l15) * 32 + lg * 8]);
            float4 b1q = *reinterpret_cast<const float4*>(&b1[t * 16 + lg * 4]);
            #pragma unroll
            for (int et = 0; et < 4; ++et) {
                int le = w * 64 + et * 16 + l15;   // local edge row in sAmem
                f32x4 c = { b1q.x, b1q.y, b1q.z, b1q.w };
                c = __builtin_amdgcn_mfma_f32_16x16x32_bf16(w1f, aef[et], c, 0, 0, 0);
                uint32_t u0 = (uint32_t)f32_bf16(fmaxf(c[0], 0.f)) | ((uint32_t)f32_bf16(fmaxf(c[1], 0.f)) << 16);
                uint32_t u1 = (uint32_t)f32_bf16(fmaxf(c[2], 0.f)) | ((uint32_t)f32_bf16(fmaxf(c[3], 0.f)) << 16);
                uint2 pk = { u0, u1 };
                *reinterpret_cast<uint2*>(&sAmem[le * 128 + ((t * 16 + lg * 4) ^ key)]) = pk;
            }
        }
    }
    __syncthreads();   // relu1 visible

    // ---- aF: 4 fragment sets for this wave's 64 edges ----
    bf16x8 aF[4][4];
    #pragma unroll
    for (int et = 0; et < 4; ++et) {
        int le = w * 64 + et * 16 + l15;
        #pragma unroll
        for (int kb = 0; kb < 4; ++kb)
            aF[et][kb] = *reinterpret_cast<const bf16x8*>(
                &sAmem[le * 128 + ((kb * 32 + lg * 8) ^ key)]);
    }
    __syncthreads();   // relu1 dead -> sAmem reusable as B buffers

    stage(0, buf0);
    stage(1, buf1);
    __syncthreads();   // vmcnt drained: chunks 0,1 resident

    float msgv[4][8];
    #pragma unroll
    for (int et = 0; et < 4; ++et)
        #pragma unroll
        for (int q = 0; q < 8; ++q) msgv[et][q] = 0.f;

    // ---------- P2: 8 x 64-col chunks, double-buffered, stage-ahead-by-2, xw pipelined ----------
    float2 xwc0 = *reinterpret_cast<const float2*>(&nf[sa[0] * 16]);
    float2 xwc1 = *reinterpret_cast<const float2*>(&nf[sa[1] * 16]);
    float2 xwc2 = *reinterpret_cast<const float2*>(&nf[sa[2] * 16]);
    float2 xwc3 = *reinterpret_cast<const float2*>(&nf[sa[3] * 16]);

    #pragma unroll 1
    for (int c = 0; c < 8; ++c) {
        const unsigned short* sCur = (c & 1) ? buf1 : buf0;

        float2 xwn0 = xwc0, xwn1 = xwc1, xwn2 = xwc2, xwn3 = xwc3;
        if (c < 7) {
            xwn0 = *reinterpret_cast<const float2*>(&nf[sa[0] * 16 + (c + 1) * 2]);
            xwn1 = *reinterpret_cast<const float2*>(&nf[sa[1] * 16 + (c + 1) * 2]);
            xwn2 = *reinterpret_cast<const float2*>(&nf[sa[2] * 16 + (c + 1) * 2]);
            xwn3 = *reinterpret_cast<const float2*>(&nf[sa[3] * 16 + (c + 1) * 2]);
        }

        #pragma unroll
        for (int f = 0; f < 4; ++f) {
            int n = f * 16 + l15;                 // local row; row&15 == l15
            bf16x8 bw[4];
            #pragma unroll
            for (int kb = 0; kb < 4; ++kb)
                bw[kb] = *reinterpret_cast<const bf16x8*>(
                    &sCur[n * 128 + ((kb * 32 + lg * 8) ^ key2)]);
            float4 b2q = *reinterpret_cast<const float4*>(&b2[c * 64 + f * 16 + lg * 4]);
            f32x4 a0 = { b2q.x, b2q.y, b2q.z, b2q.w };
            f32x4 a1 = a0, a2 = a0, a3 = a0;
            #pragma unroll
            for (int kb = 0; kb < 4; ++kb) {
                a0 = __builtin_amdgcn_mfma_f32_16x16x32_bf16(bw[kb], aF[0][kb], a0, 0, 0, 0);
                a1 = __builtin_amdgcn_mfma_f32_16x16x32_bf16(bw[kb], aF[1][kb], a1, 0, 0, 0);
                a2 = __builtin_amdgcn_mfma_f32_16x16x32_bf16(bw[kb], aF[2][kb], a2, 0, 0, 0);
                a3 = __builtin_amdgcn_mfma_f32_16x16x32_bf16(bw[kb], aF[3][kb], a3, 0, 0, 0);
            }
            // global n = c*64 + f*16 + lg*4 + r ; i = c*2 + (f>>1) ; h = (f&1)*16 + lg*4 + r
            const int s = (f & 1) * 4;
            const int xs = f >> 1;
            const float x0 = xs ? xwc0.y : xwc0.x;
            const float x1 = xs ? xwc1.y : xwc1.x;
            const float x2 = xs ? xwc2.y : xwc2.x;
            const float x3 = xs ? xwc3.y : xwc3.x;
            #pragma unroll
            for (int r = 0; r < 4; ++r) {
                msgv[0][s + r] += x0 * a0[r];
                msgv[1][s + r] += x1 * a1[r];
                msgv[2][s + r] += x2 * a2[r];
                msgv[3][s + r] += x3 * a3[r];
            }
        }

        if (c < 7) {
            __syncthreads();                       // all waves done reading sCur
            if (c + 2 < 8) stage(c + 2, (c & 1) ? buf1 : buf0);  // overlaps compute(c+1)
        }
        xwc0 = xwn0; xwc1 = xwn1; xwc2 = xwn2; xwc3 = xwn3;
    }

    // ---------- store msg (f32): lane owns 4 edges, h-slice lg*4 + {0,16}; tail-guarded ----------
    #pragma unroll
    for (int et = 0; et < 4; ++et) {
        if (!ve[et]) continue;
        int e = eidx4[et];
        #pragma unroll
        for (int half = 0; half < 2; ++half) {
            float4 o = { msgv[et][half * 4 + 0], msgv[et][half * 4 + 1],
                         msgv[et][half * 4 + 2], msgv[et][half * 4 + 3] };
            *reinterpret_cast<float4*>(&msg[e * 32 + half * 16 + lg * 4]) = o;
        }
    }
}

// ---- aggregate: h[n][q*4..q*4+3] = relu(mean over slot edges of msg + conv_b), float4 ----
__global__ __launch_bounds__(256) void aggregate_h(
    const float* __restrict__ msg, const int* __restrict__ cursor,
    const int* __restrict__ slots, const float* __restrict__ conv_b,
    float* __restrict__ h)
{
    int t = blockIdx.x * 256 + threadIdx.x;
    int n = t >> 3;
    if (n >= N_NODES) return;
    int q = t & 7;                              // h-quad index
    int d = cursor[n];
    int dm = d < CAP ? d : CAP;
    const int* row = &slots[n * CAP];
    float4 s = { 0.f, 0.f, 0.f, 0.f };
    int j = 0;
    for (; j + 2 <= dm; j += 2) {
        int ee0 = row[j], ee1 = row[j + 1];
        float4 v0 = *reinterpret_cast<const float4*>(&msg[ee0 * 32 + q * 4]);
        float4 v1 = *reinterpret_cast<const float4*>(&msg[ee1 * 32 + q * 4]);
        s.x += v0.x + v1.x; s.y += v0.y + v1.y; s.z += v0.z + v1.z; s.w += v0.w + v1.w;
    }
    if (j < dm) {
        float4 v = *reinterpret_cast<const float4*>(&msg[row[j] * 32 + q * 4]);
        s.x += v.x; s.y += v.y; s.z += v.z; s.w += v.w;
    }
    float inv = 1.0f / fmaxf((float)d, 1.f);
    float4 cb = *reinterpret_cast<const float4*>(&conv_b[q * 4]);
    float4 o;
    o.x = fmaxf(s.x * inv + cb.x, 0.f);
    o.y = fmaxf(s.y * inv + cb.y, 0.f);
    o.z = fmaxf(s.z * inv + cb.z, 0.f);
    o.w = fmaxf(s.w * inv + cb.w, 0.f);
    *reinterpret_cast<float4*>(&h[n * 32 + q * 4]) = o;
}

// ---- classifier (MFMA, direct-gather fragments): 64 edges per 256-thread block ----
// R17-verified (absmax unchanged): D[hid][edge], lane l15 = edge; B-fragments from
// global gathers (kb0 = h[sn], kb1 = h[dn], kb2 = ef | 0-pad); A = w1c bf16 [32][96].
__global__ __launch_bounds__(256) void classifier(
    const float* __restrict__ h, const float* __restrict__ ef,
    const int* __restrict__ src, const int* __restrict__ dst, const int* __restrict__ eidx,
    const unsigned short* __restrict__ w1c, const float* __restrict__ b1,
    const float* __restrict__ w2, const float* __restrict__ b2, float* __restrict__ out)
{
    const int tid  = threadIdx.x;
    const int lane = tid & 63;
    const int wid  = tid >> 6;      // wave 0..3
    const int l15  = lane & 15;
    const int lg   = lane >> 4;     // 0..3
    const int e_cls = blockIdx.x * 64 + wid * 16 + l15;
    const bool valid = e_cls < N_CLS;
    const int ec = valid ? e_cls : 0;

    const int ei = eidx[ec];
    const int sn = src[ei];
    const int dn = dst[ei];

    bf16x8 bf[3];
    {
        float4 f0 = *reinterpret_cast<const float4*>(&h[sn * 32 + lg * 8]);
        float4 f1 = *reinterpret_cast<const float4*>(&h[sn * 32 + lg * 8 + 4]);
        bf[0] = pack_bf16x8(f0, f1);
        float4 g0 = *reinterpret_cast<const float4*>(&h[dn * 32 + lg * 8]);
        float4 g1 = *reinterpret_cast<const float4*>(&h[dn * 32 + lg * 8 + 4]);
        bf[1] = pack_bf16x8(g0, g1);
        if (lg < 2) {
            float4 e0 = *reinterpret_cast<const float4*>(&ef[ei * 16 + lg * 8]);
            float4 e1 = *reinterpret_cast<const float4*>(&ef[ei * 16 + lg * 8 + 4]);
            bf[2] = pack_bf16x8(e0, e1);
        } else {
            bf[2] = bf16x8(0);     // K-pad (k >= 80)
        }
    }

    float hidv[2][4];
    #pragma unroll
    for (int t = 0; t < 2; ++t) {
        float4 b1q = *reinterpret_cast<const float4*>(&b1[t * 16 + lg * 4]);
        f32x4 c = { b1q.x, b1q.y, b1q.z, b1q.w };
        #pragma unroll
        for (int kb = 0; kb < 3; ++kb) {
            bf16x8 a = *reinterpret_cast<const bf16x8*>(&w1c[(t * 16 + l15) * 96 + kb * 32 + lg * 8]);
            c = __builtin_amdgcn_mfma_f32_16x16x32_bf16(a, bf[kb], c, 0, 0, 0);
        }
        #pragma unroll
        for (int r = 0; r < 4; ++r) hidv[t][r] = fmaxf(c[r], 0.f);
    }

    float p0 = 0.f, p1 = 0.f;
    #pragma unroll
    for (int t = 0; t < 2; ++t) {
        int j0 = t * 16 + lg * 4;
        float4 wq0 = *reinterpret_cast<const float4*>(&w2[j0 * 2]);      // j0, j0+1
        float4 wq1 = *reinterpret_cast<const float4*>(&w2[j0 * 2 + 4]);  // j0+2, j0+3
        p0 += hidv[t][0] * wq0.x + hidv[t][1] * wq0.z + hidv[t][2] * wq1.x + hidv[t][3] * wq1.z;
        p1 += hidv[t][0] * wq0.y + hidv[t][1] * wq0.w + hidv[t][2] * wq1.y + hidv[t][3] * wq1.w;
    }
    p0 += __shfl_xor(p0, 16); p0 += __shfl_xor(p0, 32);
    p1 += __shfl_xor(p1, 16); p1 += __shfl_xor(p1, 32);

    if (valid && lg == 0) {
        float2 o = { p0 + b2[0], p1 + b2[1] };
        *reinterpret_cast<float2*>(&out[e_cls * 2]) = o;
    }
}

extern "C" void kernel_launch(void* const* d_in, const int* in_sizes, int n_in,
                              void* d_out, int out_size, void* d_ws, size_t ws_size,
                              hipStream_t stream) {
    const float* nf     = (const float*)d_in[0];
    const float* ef     = (const float*)d_in[1];
    const int*   src    = (const int*)d_in[2];
    const int*   dst    = (const int*)d_in[3];
    const int*   eidx   = (const int*)d_in[4];
    const float* en_w1  = (const float*)d_in[5];
    const float* en_b1  = (const float*)d_in[6];
    const float* en_w2  = (const float*)d_in[7];
    const float* en_b2  = (const float*)d_in[8];
    const float* conv_b = (const float*)d_in[9];
    const float* cls_w1 = (const float*)d_in[10];
    const float* cls_b1 = (const float*)d_in[11];
    const float* cls_w2 = (const float*)d_in[12];
    const float* cls_b2 = (const float*)d_in[13];
    float* out = (float*)d_out;

    char* ws = (char*)d_ws;
    unsigned short* w2ts   = (unsigned short*)(ws);                 // 131,072 B (pre-swizzled, n&15 key)
    unsigned short* w1t    = (unsigned short*)(ws + 131072);        //   8,192 B
    unsigned short* w1c    = (unsigned short*)(ws + 139264);        //   6,144 B (cls W1 bf16, K-pad 96)
    int*            cursor = (int*)(ws + 145408);                   // 200,000 B
    int*            slots  = (int*)(ws + 345408);                   // 8,000,000 B
    float*          msgb   = (float*)(ws + 8345408);                // 51,200,000 B (f32)
    float*          h      = (float*)(ws + 59545408);               // 6,400,000 B

    hipMemsetAsync(cursor, 0, N_NODES * sizeof(int), stream);
    prep_and_slots<<<(N_EDGES + 255) / 256, 256, 0, stream>>>(en_w2, en_w1, cls_w1, dst,
                                                              w2ts, w1t, w1c, cursor, slots);
    fused_msg<<<FUSED_BLOCKS, 256, 0, stream>>>(nf, ef, src, w1t, en_b1, w2ts, en_b2, msgb);
    aggregate_h<<<(N_NODES * 8 + 255) / 256, 256, 0, stream>>>(msgb, cursor, slots, conv_b, h);
    classifier<<<(N_CLS + 63) / 64, 256, 0, stream>>>(h, ef, src, dst, eidx,
                                                      w1c, cls_b1, cls_w2, cls_b2, out);
}

// Round 21
// 135.020 us; speedup vs baseline: 1.0497x; 1.0497x over previous
//
#include <hip/hip_runtime.h>
#include <stdint.h>

#define N_NODES   50000
#define N_EDGES   400000
#define IN_FEATS  16
#define HIDDEN    32
#define K1        128      // EDGE_MLP_HID
#define NOUT      512      // IN_FEATS*HIDDEN
#define N_CLS     100000
#define CAP       40       // max degree slots (Poisson(8): P(deg>40) ~ 0)
#define TILE_E    128
#define FUSED_BLOCKS (N_EDGES / TILE_E)   // 3125

typedef float  f32x4  __attribute__((ext_vector_type(4)));
typedef __bf16 bf16x8 __attribute__((ext_vector_type(8)));

__device__ __forceinline__ unsigned short f32_bf16(float f) {
    union { float f; uint32_t u; } c; c.f = f;
    uint32_t r = c.u + 0x7fffu + ((c.u >> 16) & 1u);
    return (unsigned short)(r >> 16);
}

// async global->LDS, 16B per lane; LDS dest is wave-uniform base + lane*16
__device__ __forceinline__ void gload_lds16(const unsigned short* g, unsigned short* l) {
    __builtin_amdgcn_global_load_lds(
        (const __attribute__((address_space(1))) unsigned int*)(g),
        (__attribute__((address_space(3))) unsigned int*)(l),
        16, 0, 0);
}

__device__ __forceinline__ bf16x8 pack_bf16x8(float4 f0, float4 f1) {
    unsigned short t8[8] = { f32_bf16(f0.x), f32_bf16(f0.y), f32_bf16(f0.z), f32_bf16(f0.w),
                             f32_bf16(f1.x), f32_bf16(f1.y), f32_bf16(f1.z), f32_bf16(f1.w) };
    return *reinterpret_cast<const bf16x8*>(t8);
}

// ---- merged prep: weights transpose/convert + dst bucketing (coalesced reads) ----
// w2ts: W2 [128,512] -> bf16 [512,128], PRE-SWIZZLED k ^= (n&15)<<3 (R10/R11-verified).
// w1t:  W1 [16,128] -> bf16 [128,32] (K padded 16->32), linear.
// w1c:  cls_w1 [80,32] -> bf16 [32 hid][96 K] (K padded 80->96), for MFMA classifier.
__global__ void prep_and_slots(const float* __restrict__ w2, const float* __restrict__ w1,
                               const float* __restrict__ cw1, const int* __restrict__ dst,
                               unsigned short* __restrict__ w2ts, unsigned short* __restrict__ w1t,
                               unsigned short* __restrict__ w1c,
                               int* __restrict__ cursor, int* __restrict__ slots) {
    int gid = blockIdx.x * 256 + threadIdx.x;
    if (gid < NOUT * K1) {
        int k = gid >> 9, n = gid & 511;               // read w2[k*512+n] coalesced in n
        w2ts[n * 128 + (k ^ ((n & 15) << 3))] = f32_bf16(w2[k * 512 + n]);
    } else if (gid < NOUT * K1 + 4096) {
        int t = gid - NOUT * K1;
        int k = t >> 7, n = t & 127;                   // read w1[k*128+n] coalesced in n
        w1t[n * 32 + k] = (k < 16) ? f32_bf16(w1[k * 128 + n]) : (unsigned short)0;
    } else if (gid < NOUT * K1 + 4096 + 3072) {
        int t = gid - (NOUT * K1 + 4096);
        int k = t >> 5, hid = t & 31;                  // read cw1[k*32+hid] coalesced in hid
        w1c[hid * 96 + k] = (k < 80) ? f32_bf16(cw1[k * 32 + hid]) : (unsigned short)0;
    }
    if (gid < N_EDGES) {
        int d = dst[gid];
        int pos = atomicAdd(&cursor[d], 1);
        if (pos < CAP) slots[d * CAP + pos] = gid;
    }
}

// ---- fused: edge MLP (MFMA, swapped operands) + per-edge matvec ----
// Champion configuration (R19: fused 82-84us, VGPR 64, zero spill, 36% occ).
// Session ledger: 8 structural variants (occupancy 17-43%, 2/4-way reuse, setprio,
// bf16 msg, persistent/churn, atomics/sort) all land 83-88us — latency equilibrium.
// NOTE: min-waves MUST stay 4 — (256,5) forced VGPR 48 and spilled (R13).
__global__ __launch_bounds__(256, 4) void fused_msg(
    const float* __restrict__ nf, const float* __restrict__ ef,
    const int* __restrict__ src,
    const unsigned short* __restrict__ w1t, const float* __restrict__ b1,
    const unsigned short* __restrict__ w2ts, const float* __restrict__ b2,
    float* __restrict__ msg)
{
    __shared__ __align__(16) unsigned short sAmem[128 * 128]; // 32KB: relu1, then B buf0|buf1

    const int tid  = threadIdx.x;
    const int lane = tid & 63;
    const int w    = tid >> 6;      // wave 0..3
    const int l15  = lane & 15;
    const int lg   = lane >> 4;     // 0..3
    const int key  = (l15 & 7) << 3;   // relu1 (sA) swizzle key (write+read paired)
    const int key2 = l15 << 3;         // B swizzle key, full 4-bit (matches w2ts pre-swizzle)
    const int e0   = blockIdx.x * TILE_E;

    unsigned short* buf0 = sAmem;            // 16KB (64 rows x 128)
    unsigned short* buf1 = sAmem + 8192;     // 16KB

    auto stage = [&](int cc, unsigned short* buf) {
        #pragma unroll
        for (int i = 0; i < 4; ++i)
            gload_lds16(&w2ts[cc * 8192 + (w * 4 + i) * 512 + lane * 8],
                        &buf[(w * 4 + i) * 512]);
    };

    const int ea = e0 + w * 32 + l15;
    const int eb = ea + 16;
    const int sa0 = src[ea];
    const int sa1 = src[eb];

    // ---------- P1 (own-edges): relu1 for edges ea/eb across ALL 8 n1-tiles ----------
    {
        bf16x8 aef[2];
        #pragma unroll
        for (int m = 0; m < 2; ++m) {
            int e = m ? eb : ea;
            if (lg < 2) {
                float4 f0 = *reinterpret_cast<const float4*>(&ef[e * 16 + lg * 8]);
                float4 f1 = *reinterpret_cast<const float4*>(&ef[e * 16 + lg * 8 + 4]);
                aef[m] = pack_bf16x8(f0, f1);
            } else {
                aef[m] = bf16x8(0);   // K-pad (k >= 16)
            }
        }
        #pragma unroll
        for (int t = 0; t < 8; ++t) {
            bf16x8 w1f = *reinterpret_cast<const bf16x8*>(&w1t[(t * 16 + l15) * 32 + lg * 8]);
            float4 b1q = *reinterpret_cast<const float4*>(&b1[t * 16 + lg * 4]);
            #pragma unroll
            for (int m = 0; m < 2; ++m) {
                int le = w * 32 + m * 16 + l15;   // local edge row in sAmem
                f32x4 c = { b1q.x, b1q.y, b1q.z, b1q.w };
                c = __builtin_amdgcn_mfma_f32_16x16x32_bf16(w1f, aef[m], c, 0, 0, 0);
                uint32_t u0 = (uint32_t)f32_bf16(fmaxf(c[0], 0.f)) | ((uint32_t)f32_bf16(fmaxf(c[1], 0.f)) << 16);
                uint32_t u1 = (uint32_t)f32_bf16(fmaxf(c[2], 0.f)) | ((uint32_t)f32_bf16(fmaxf(c[3], 0.f)) << 16);
                uint2 pk = { u0, u1 };
                *reinterpret_cast<uint2*>(&sAmem[le * 128 + ((t * 16 + lg * 4) ^ key)]) = pk;
            }
        }
    }
    __syncthreads();   // relu1 visible

    bf16x8 aF[2][4];
    #pragma unroll
    for (int et = 0; et < 2; ++et) {
        int le = w * 32 + et * 16 + l15;
        #pragma unroll
        for (int kb = 0; kb < 4; ++kb)
            aF[et][kb] = *reinterpret_cast<const bf16x8*>(
                &sAmem[le * 128 + ((kb * 32 + lg * 8) ^ key)]);
    }
    __syncthreads();   // relu1 dead -> sAmem reusable as B buffers

    stage(0, buf0);
    stage(1, buf1);
    __syncthreads();   // vmcnt drained: chunks 0,1 resident

    float msgv[2][8];
    #pragma unroll
    for (int et = 0; et < 2; ++et)
        #pragma unroll
        for (int q = 0; q < 8; ++q) msgv[et][q] = 0.f;

    float2 xw0c = *reinterpret_cast<const float2*>(&nf[sa0 * 16]);
    float2 xw1c = *reinterpret_cast<const float2*>(&nf[sa1 * 16]);

    #pragma unroll 1
    for (int c = 0; c < 8; ++c) {
        const unsigned short* sCur = (c & 1) ? buf1 : buf0;

        float2 xw0n = xw0c, xw1n = xw1c;
        if (c < 7) {
            xw0n = *reinterpret_cast<const float2*>(&nf[sa0 * 16 + (c + 1) * 2]);
            xw1n = *reinterpret_cast<const float2*>(&nf[sa1 * 16 + (c + 1) * 2]);
        }

        #pragma unroll
        for (int f = 0; f < 4; ++f) {
            int n = f * 16 + l15;
            bf16x8 bw[4];
            #pragma unroll
            for (int kb = 0; kb < 4; ++kb)
                bw[kb] = *reinterpret_cast<const bf16x8*>(
                    &sCur[n * 128 + ((kb * 32 + lg * 8) ^ key2)]);
            float4 b2q = *reinterpret_cast<const float4*>(&b2[c * 64 + f * 16 + lg * 4]);
            f32x4 a0 = { b2q.x, b2q.y, b2q.z, b2q.w };
            f32x4 a1 = a0;
            #pragma unroll
            for (int kb = 0; kb < 4; ++kb) {
                a0 = __builtin_amdgcn_mfma_f32_16x16x32_bf16(bw[kb], aF[0][kb], a0, 0, 0, 0);
                a1 = __builtin_amdgcn_mfma_f32_16x16x32_bf16(bw[kb], aF[1][kb], a1, 0, 0, 0);
            }
            const float x0 = (f >> 1) ? xw0c.y : xw0c.x;
            const float x1 = (f >> 1) ? xw1c.y : xw1c.x;
            const int s = (f & 1) * 4;
            #pragma unroll
            for (int r = 0; r < 4; ++r) {
                msgv[0][s + r] += x0 * a0[r];
                msgv[1][s + r] += x1 * a1[r];
            }
        }

        if (c < 7) {
            __syncthreads();
            if (c + 2 < 8) stage(c + 2, (c & 1) ? buf1 : buf0);
        }
        xw0c = xw0n; xw1c = xw1n;
    }

    #pragma unroll
    for (int et = 0; et < 2; ++et) {
        int e = et ? eb : ea;
        #pragma unroll
        for (int half = 0; half < 2; ++half) {
            float4 o = { msgv[et][half * 4 + 0], msgv[et][half * 4 + 1],
                         msgv[et][half * 4 + 2], msgv[et][half * 4 + 3] };
            *reinterpret_cast<float4*>(&msg[e * 32 + half * 16 + lg * 4]) = o;
        }
    }
}

// ---- aggregate: h[n][q*4..q*4+3] = relu(mean over slot edges of msg + conv_b), float4 ----
__global__ __launch_bounds__(256) void aggregate_h(
    const float* __restrict__ msg, const int* __restrict__ cursor,
    const int* __restrict__ slots, const float* __restrict__ conv_b,
    float* __restrict__ h)
{
    int t = blockIdx.x * 256 + threadIdx.x;
    int n = t >> 3;
    if (n >= N_NODES) return;
    int q = t & 7;                              // h-quad index
    int d = cursor[n];
    int dm = d < CAP ? d : CAP;
    const int* row = &slots[n * CAP];
    float4 s = { 0.f, 0.f, 0.f, 0.f };
    int j = 0;
    for (; j + 2 <= dm; j += 2) {
        int ee0 = row[j], ee1 = row[j + 1];
        float4 v0 = *reinterpret_cast<const float4*>(&msg[ee0 * 32 + q * 4]);
        float4 v1 = *reinterpret_cast<const float4*>(&msg[ee1 * 32 + q * 4]);
        s.x += v0.x + v1.x; s.y += v0.y + v1.y; s.z += v0.z + v1.z; s.w += v0.w + v1.w;
    }
    if (j < dm) {
        float4 v = *reinterpret_cast<const float4*>(&msg[row[j] * 32 + q * 4]);
        s.x += v.x; s.y += v.y; s.z += v.z; s.w += v.w;
    }
    float inv = 1.0f / fmaxf((float)d, 1.f);
    float4 cb = *reinterpret_cast<const float4*>(&conv_b[q * 4]);
    float4 o;
    o.x = fmaxf(s.x * inv + cb.x, 0.f);
    o.y = fmaxf(s.y * inv + cb.y, 0.f);
    o.z = fmaxf(s.z * inv + cb.z, 0.f);
    o.w = fmaxf(s.w * inv + cb.w, 0.f);
    *reinterpret_cast<float4*>(&h[n * 32 + q * 4]) = o;
}

// ---- classifier (MFMA, direct-gather fragments): 64 edges per 256-thread block ----
// R17-verified (absmax unchanged): D[hid][edge], lane l15 = edge; B-fragments from
// global gathers (kb0 = h[sn], kb1 = h[dn], kb2 = ef | 0-pad); A = w1c bf16 [32][96].
__global__ __launch_bounds__(256) void classifier(
    const float* __restrict__ h, const float* __restrict__ ef,
    const int* __restrict__ src, const int* __restrict__ dst, const int* __restrict__ eidx,
    const unsigned short* __restrict__ w1c, const float* __restrict__ b1,
    const float* __restrict__ w2, const float* __restrict__ b2, float* __restrict__ out)
{
    const int tid  = threadIdx.x;
    const int lane = tid & 63;
    const int wid  = tid >> 6;      // wave 0..3
    const int l15  = lane & 15;
    const int lg   = lane >> 4;     // 0..3
    const int e_cls = blockIdx.x * 64 + wid * 16 + l15;
    const bool valid = e_cls < N_CLS;
    const int ec = valid ? e_cls : 0;

    const int ei = eidx[ec];
    const int sn = src[ei];
    const int dn = dst[ei];

    bf16x8 bf[3];
    {
        float4 f0 = *reinterpret_cast<const float4*>(&h[sn * 32 + lg * 8]);
        float4 f1 = *reinterpret_cast<const float4*>(&h[sn * 32 + lg * 8 + 4]);
        bf[0] = pack_bf16x8(f0, f1);
        float4 g0 = *reinterpret_cast<const float4*>(&h[dn * 32 + lg * 8]);
        float4 g1 = *reinterpret_cast<const float4*>(&h[dn * 32 + lg * 8 + 4]);
        bf[1] = pack_bf16x8(g0, g1);
        if (lg < 2) {
            float4 e0 = *reinterpret_cast<const float4*>(&ef[ei * 16 + lg * 8]);
            float4 e1 = *reinterpret_cast<const float4*>(&ef[ei * 16 + lg * 8 + 4]);
            bf[2] = pack_bf16x8(e0, e1);
        } else {
            bf[2] = bf16x8(0);     // K-pad (k >= 80)
        }
    }

    float hidv[2][4];
    #pragma unroll
    for (int t = 0; t < 2; ++t) {
        float4 b1q = *reinterpret_cast<const float4*>(&b1[t * 16 + lg * 4]);
        f32x4 c = { b1q.x, b1q.y, b1q.z, b1q.w };
        #pragma unroll
        for (int kb = 0; kb < 3; ++kb) {
            bf16x8 a = *reinterpret_cast<const bf16x8*>(&w1c[(t * 16 + l15) * 96 + kb * 32 + lg * 8]);
            c = __builtin_amdgcn_mfma_f32_16x16x32_bf16(a, bf[kb], c, 0, 0, 0);
        }
        #pragma unroll
        for (int r = 0; r < 4; ++r) hidv[t][r] = fmaxf(c[r], 0.f);
    }

    float p0 = 0.f, p1 = 0.f;
    #pragma unroll
    for (int t = 0; t < 2; ++t) {
        int j0 = t * 16 + lg * 4;
        float4 wq0 = *reinterpret_cast<const float4*>(&w2[j0 * 2]);      // j0, j0+1
        float4 wq1 = *reinterpret_cast<const float4*>(&w2[j0 * 2 + 4]);  // j0+2, j0+3
        p0 += hidv[t][0] * wq0.x + hidv[t][1] * wq0.z + hidv[t][2] * wq1.x + hidv[t][3] * wq1.z;
        p1 += hidv[t][0] * wq0.y + hidv[t][1] * wq0.w + hidv[t][2] * wq1.y + hidv[t][3] * wq1.w;
    }
    p0 += __shfl_xor(p0, 16); p0 += __shfl_xor(p0, 32);
    p1 += __shfl_xor(p1, 16); p1 += __shfl_xor(p1, 32);

    if (valid && lg == 0) {
        float2 o = { p0 + b2[0], p1 + b2[1] };
        *reinterpret_cast<float2*>(&out[e_cls * 2]) = o;
    }
}

extern "C" void kernel_launch(void* const* d_in, const int* in_sizes, int n_in,
                              void* d_out, int out_size, void* d_ws, size_t ws_size,
                              hipStream_t stream) {
    const float* nf     = (const float*)d_in[0];
    const float* ef     = (const float*)d_in[1];
    const int*   src    = (const int*)d_in[2];
    const int*   dst    = (const int*)d_in[3];
    const int*   eidx   = (const int*)d_in[4];
    const float* en_w1  = (const float*)d_in[5];
    const float* en_b1  = (const float*)d_in[6];
    const float* en_w2  = (const float*)d_in[7];
    const float* en_b2  = (const float*)d_in[8];
    const float* conv_b = (const float*)d_in[9];
    const float* cls_w1 = (const float*)d_in[10];
    const float* cls_b1 = (const float*)d_in[11];
    const float* cls_w2 = (const float*)d_in[12];
    const float* cls_b2 = (const float*)d_in[13];
    float* out = (float*)d_out;

    char* ws = (char*)d_ws;
    unsigned short* w2ts   = (unsigned short*)(ws);                 // 131,072 B (pre-swizzled, n&15 key)
    unsigned short* w1t    = (unsigned short*)(ws + 131072);        //   8,192 B
    unsigned short* w1c    = (unsigned short*)(ws + 139264);        //   6,144 B (cls W1 bf16, K-pad 96)
    int*            cursor = (int*)(ws + 145408);                   // 200,000 B
    int*            slots  = (int*)(ws + 345408);                   // 8,000,000 B
    float*          msgb   = (float*)(ws + 8345408);                // 51,200,000 B (f32)
    float*          h      = (float*)(ws + 59545408);               // 6,400,000 B

    hipMemsetAsync(cursor, 0, N_NODES * sizeof(int), stream);
    prep_and_slots<<<(N_EDGES + 255) / 256, 256, 0, stream>>>(en_w2, en_w1, cls_w1, dst,
                                                              w2ts, w1t, w1c, cursor, slots);
    fused_msg<<<FUSED_BLOCKS, 256, 0, stream>>>(nf, ef, src, w1t, en_b1, w2ts, en_b2, msgb);
    aggregate_h<<<(N_NODES * 8 + 255) / 256, 256, 0, stream>>>(msgb, cursor, slots, conv_b, h);
    classifier<<<(N_CLS + 63) / 64, 256, 0, stream>>>(h, ef, src, dst, eidx,
                                                      w1c, cls_b1, cls_w2, cls_b2, out);
}